// Round 1
// baseline (324.072 us; speedup 1.0000x reference)
//
#include <hip/hip_runtime.h>
#include <math.h>

// ---------------------------------------------------------------------------
// Problem constants: D = 128, F = 65.  M = 30000 rows, K = 1024 (img) / 768 (txt)
// Pipeline: proj = table @ W + b  ->  rfft(128, ortho) -> rotate/mask -> irfft.
// proj is staged in d_out and transformed in place by the spectral kernel.
// ---------------------------------------------------------------------------

#define GB_BM 64
#define GB_KS 32

__global__ __launch_bounds__(256) void gemm_bias_kernel(
    const float* __restrict__ A, const float* __restrict__ W,
    const float* __restrict__ bias, float* __restrict__ out,
    int M, int K) {
  __shared__ float As[GB_KS][GB_BM + 4];   // transposed [k][row], stride 68 (16B-aligned reads)
  __shared__ float Bs[GB_KS][128];
  const int tid  = threadIdx.x;
  const int row0 = blockIdx.x * GB_BM;
  const int c4 = (tid & 31) * 4;       // output col group (0..124)
  const int r0 = (tid >> 5) * 8;       // output row group (0..56)
  const int arow = tid >> 2;           // A-stage row (0..63)
  const int kg   = (tid & 3) * 8;      // A-stage k-group (0,8,16,24)
  const int bk0  = tid >> 5;           // B-stage k row (0..7)

  float4 acc[8];
#pragma unroll
  for (int i = 0; i < 8; ++i) acc[i] = make_float4(0.f, 0.f, 0.f, 0.f);

  for (int k0 = 0; k0 < K; k0 += GB_KS) {
    // stage A tile (transposed into LDS)
    float4 av0, av1;
    {
      const int grow = row0 + arow;
      if (grow < M) {
        const float* ap = A + (size_t)grow * K + k0 + kg;
        av0 = *(const float4*)ap;
        av1 = *(const float4*)(ap + 4);
      } else {
        av0 = make_float4(0.f, 0.f, 0.f, 0.f);
        av1 = av0;
      }
    }
    As[kg + 0][arow] = av0.x; As[kg + 1][arow] = av0.y;
    As[kg + 2][arow] = av0.z; As[kg + 3][arow] = av0.w;
    As[kg + 4][arow] = av1.x; As[kg + 5][arow] = av1.y;
    As[kg + 6][arow] = av1.z; As[kg + 7][arow] = av1.w;
    // stage B tile (linear)
#pragma unroll
    for (int p = 0; p < 4; ++p) {
      const int bk = bk0 + p * 8;
      *(float4*)&Bs[bk][c4] = *(const float4*)&W[(size_t)(k0 + bk) * 128 + c4];
    }
    __syncthreads();
#pragma unroll
    for (int kk = 0; kk < GB_KS; ++kk) {
      const float4 a0 = *(const float4*)&As[kk][r0];
      const float4 a1 = *(const float4*)&As[kk][r0 + 4];
      const float4 b  = *(const float4*)&Bs[kk][c4];
      const float ar[8] = {a0.x, a0.y, a0.z, a0.w, a1.x, a1.y, a1.z, a1.w};
#pragma unroll
      for (int i = 0; i < 8; ++i) {
        acc[i].x = fmaf(ar[i], b.x, acc[i].x);
        acc[i].y = fmaf(ar[i], b.y, acc[i].y);
        acc[i].z = fmaf(ar[i], b.z, acc[i].z);
        acc[i].w = fmaf(ar[i], b.w, acc[i].w);
      }
    }
    __syncthreads();
  }
  const float4 bv = *(const float4*)&bias[c4];
#pragma unroll
  for (int i = 0; i < 8; ++i) {
    const int grow = row0 + r0 + i;
    if (grow < M) {
      float4 o;
      o.x = acc[i].x + bv.x; o.y = acc[i].y + bv.y;
      o.z = acc[i].z + bv.z; o.w = acc[i].w + bv.w;
      *(float4*)&out[(size_t)grow * 128 + c4] = o;
    }
  }
}

// ---------------------------------------------------------------------------
// Spectral kernel: 1 wave per row (4 rows / 256-thread block), in-place on d_out.
// rfft (ortho) -> rot/AVRF/MSC mask -> irfft (ortho).
// ---------------------------------------------------------------------------
__global__ __launch_bounds__(256) void spectral_kernel(
    float* io_img, float* io_txt,
    const float* __restrict__ avrf_img, const float* __restrict__ avrf_txt,
    const float* __restrict__ avg_R, const float* __restrict__ psi,
    const float* __restrict__ lamw, int M) {
  __shared__ float twc[128], tws[128];       // cos/sin(2*pi*n/128)
  __shared__ float xs[4][2][128];            // per wave: img,txt rows
  __shared__ float4 spec[4][66];             // per wave, per freq: (i_re,i_im,t_re,t_im)

  const int tid = threadIdx.x;
  if (tid < 128) {
    float s, c;
    sincosf(0.04908738521234052f * (float)tid, &s, &c);  // 2*pi/128
    twc[tid] = c; tws[tid] = s;
  }
  const int wave = tid >> 6;
  const int lane = tid & 63;
  const int row  = blockIdx.x * 4 + wave;
  const bool valid = row < M;

  if (valid) {
    const size_t base = (size_t)row * 128;
    xs[wave][0][lane]      = io_img[base + lane];
    xs[wave][0][lane + 64] = io_img[base + lane + 64];
    xs[wave][1][lane]      = io_txt[base + lane];
    xs[wave][1][lane + 64] = io_txt[base + lane + 64];
  } else {
    xs[wave][0][lane] = 0.f; xs[wave][0][lane + 64] = 0.f;
    xs[wave][1][lane] = 0.f; xs[wave][1][lane + 64] = 0.f;
  }
  __syncthreads();

  // ---- forward DFT: lane = freq k (0..63); X[k] = sum_n x[n] e^{-2pi i k n/128}
  const int k = lane;
  const float wr = twc[k], wi = -tws[k];     // e^{-2pi i k/128}
  float air = 0.f, aii = 0.f, atr = 0.f, ati = 0.f;
  for (int n8 = 0; n8 < 128; n8 += 8) {
    const int idx = (k * n8) & 127;          // resync rotation from table
    float cr = twc[idx], ci = -tws[idx];
    float xi[8], xt[8];
    *(float4*)&xi[0] = *(const float4*)&xs[wave][0][n8];
    *(float4*)&xi[4] = *(const float4*)&xs[wave][0][n8 + 4];
    *(float4*)&xt[0] = *(const float4*)&xs[wave][1][n8];
    *(float4*)&xt[4] = *(const float4*)&xs[wave][1][n8 + 4];
#pragma unroll
    for (int j = 0; j < 8; ++j) {
      air = fmaf(xi[j], cr, air);
      aii = fmaf(xi[j], ci, aii);
      atr = fmaf(xt[j], cr, atr);
      ati = fmaf(xt[j], ci, ati);
      if (j < 7) {
        const float ncr = cr * wr - ci * wi;
        ci = cr * wi + ci * wr;
        cr = ncr;
      }
    }
  }
  // ---- Nyquist bin X[64] = sum_n (-1)^n x[n] (purely real): parity shuffle-reduce
  float pi_ = xs[wave][0][lane] + xs[wave][0][lane + 64];
  float pt_ = xs[wave][1][lane] + xs[wave][1][lane + 64];
  if (lane & 1) { pi_ = -pi_; pt_ = -pt_; }
#pragma unroll
  for (int off = 32; off > 0; off >>= 1) {
    pi_ += __shfl_xor(pi_, off);
    pt_ += __shfl_xor(pt_, off);
  }
  const float scale = 0.08838834764831845f;  // 1/sqrt(128)  (norm="ortho")
  air *= scale; aii *= scale; atr *= scale; ati *= scale;
  pi_ *= scale; pt_ *= scale;

  // lambda softmax (uniform across lanes)
  const float l0 = lamw[0], l1 = lamw[1];
  const float mxl = fmaxf(l0, l1);
  const float e0 = expf(l0 - mxl), e1 = expf(l1 - mxl);
  const float inv = 1.f / (e0 + e1);
  const float lam0 = e0 * inv, lam1 = e1 * inv;

  // ---- rotation + AVRF + MSC mask, freq k (lane-local)
  {
    const float phi = avg_R[k] * 0.5f + psi[k];
    float sp, cp; sincosf(phi, &sp, &cp);
    // rot = e^{-i phi}; APC_img = X_img * rot; APC_txt = X_txt * conj(rot)
    const float Air = air * cp + aii * sp;
    const float Aii = aii * cp - air * sp;
    const float Atr = atr * cp - ati * sp;
    const float Ati = ati * cp + atr * sp;
    const float cre = Air * Atr + Aii * Ati;
    const float cim = Aii * Atr - Air * Ati;
    const float pa = Air * Air + Aii * Aii;
    const float pb = Atr * Atr + Ati * Ati;
    const float msc = (cre * cre + cim * cim) / (pa * pb + 1e-8f);
    const float mi = lam0 * avrf_img[k] + lam1 * msc;
    const float mt = lam0 * avrf_txt[k] + lam1 * msc;
    spec[wave][k] = make_float4(Air * mi, Aii * mi, Atr * mt, Ati * mt);
  }
  if (lane == 0) {   // freq 64 (Nyquist)
    const float phi = avg_R[64] * 0.5f + psi[64];
    float sp, cp; sincosf(phi, &sp, &cp);
    const float Air = pi_ * cp;
    const float Aii = -pi_ * sp;
    const float Atr = pt_ * cp;
    const float Ati = pt_ * sp;
    const float cre = Air * Atr + Aii * Ati;
    const float cim = Aii * Atr - Air * Ati;
    const float pa = Air * Air + Aii * Aii;
    const float pb = Atr * Atr + Ati * Ati;
    const float msc = (cre * cre + cim * cim) / (pa * pb + 1e-8f);
    const float mi = lam0 * avrf_img[64] + lam1 * msc;
    const float mt = lam0 * avrf_txt[64] + lam1 * msc;
    spec[wave][64] = make_float4(Air * mi, Aii * mi, Atr * mt, Ati * mt);
  }
  __syncthreads();

  // ---- irfft (ortho): lane n produces out[n] and out[n+64]
  // x[m] = (1/sqrt(128)) [ Re X0 + (-1)^m Re X64 + 2 sum_{k=1}^{63} (Re Xk cos - Im Xk sin) ]
  const int n = lane;
  const float4 s0  = spec[wave][0];
  const float4 s64 = spec[wave][64];
  const float sgn = (n & 1) ? -1.f : 1.f;
  const float basei = s0.x + sgn * s64.x;
  const float baset = s0.z + sgn * s64.z;
  const float iwr = twc[n], iwi = tws[n];    // e^{+2pi i n/128}
  float tei = 0.f, toi = 0.f, tet = 0.f, tot = 0.f;
  for (int k8 = 0; k8 < 64; k8 += 8) {
    const int idx = (n * k8) & 127;
    float cr = twc[idx], ci = tws[idx];
#pragma unroll
    for (int j = 0; j < 8; ++j) {
      const int kk = k8 + j;
      if (kk >= 1) {
        const float4 sp4 = spec[wave][kk];
        const float ti = sp4.x * cr - sp4.y * ci;
        const float tt = sp4.z * cr - sp4.w * ci;
        if (kk & 1) { toi += ti; tot += tt; }
        else        { tei += ti; tet += tt; }
      }
      const float ncr = cr * iwr - ci * iwi;
      ci = cr * iwi + ci * iwr;
      cr = ncr;
    }
  }
  if (valid) {
    const size_t base = (size_t)row * 128;
    io_img[base + n]      = scale * (basei + 2.f * (tei + toi));
    io_img[base + n + 64] = scale * (basei + 2.f * (tei - toi));
    io_txt[base + n]      = scale * (baset + 2.f * (tet + tot));
    io_txt[base + n + 64] = scale * (baset + 2.f * (tet - tot));
  }
}

extern "C" void kernel_launch(void* const* d_in, const int* in_sizes, int n_in,
                              void* d_out, int out_size, void* d_ws, size_t ws_size,
                              hipStream_t stream) {
  const float* image_table = (const float*)d_in[2];
  const float* text_table  = (const float*)d_in[3];
  const float* W_img = (const float*)d_in[4];
  const float* b_img = (const float*)d_in[5];
  const float* W_txt = (const float*)d_in[6];
  const float* b_txt = (const float*)d_in[7];
  const float* avrf_img = (const float*)d_in[8];
  const float* avrf_txt = (const float*)d_in[9];
  const float* avg_R = (const float*)d_in[10];
  const float* psi = (const float*)d_in[11];
  const float* lamw = (const float*)d_in[12];

  const int M = in_sizes[0] / 128;        // 30000
  const int K_img = in_sizes[4] / 128;    // 1024
  const int K_txt = in_sizes[6] / 128;    // 768

  float* out_img = (float*)d_out;               // proj staged here, transformed in place
  float* out_txt = out_img + (size_t)M * 128;

  const dim3 blk(256);
  const int gblocks = (M + GB_BM - 1) / GB_BM;
  gemm_bias_kernel<<<gblocks, blk, 0, stream>>>(image_table, W_img, b_img, out_img, M, K_img);
  gemm_bias_kernel<<<gblocks, blk, 0, stream>>>(text_table,  W_txt, b_txt, out_txt, M, K_txt);
  spectral_kernel<<<(M + 3) / 4, blk, 0, stream>>>(out_img, out_txt,
                                                   avrf_img, avrf_txt, avg_R, psi, lamw, M);
}

// Round 2
// 220.012 us; speedup vs baseline: 1.4730x; 1.4730x over previous
//
#include <hip/hip_runtime.h>
#include <math.h>

typedef __bf16 bf16x8 __attribute__((ext_vector_type(8)));
typedef float f32x4 __attribute__((ext_vector_type(4)));
typedef unsigned short ushort_t;

// ---------------------------------------------------------------------------
// GEMM via bf16 hi/lo split MFMA:  out[M x 128] = A[M x K] @ W[K x 128] + b
// 3-term split: a*b ~= ah*bh + ah*bl + al*bh  (fp32 accumulate in MFMA)
// Tile: BM=64 x BN=128, K-step 32, 256 threads = 4 waves (2x2), wave=32x64.
// ---------------------------------------------------------------------------
#define GKS 32
#define GBM 64

__device__ inline void split2(float v, ushort_t& h, ushort_t& l) {
  unsigned u = __float_as_uint(v);
  h = (ushort_t)(u >> 16);                       // truncated bf16 hi
  float hf = __uint_as_float(u & 0xFFFF0000u);
  float lo = v - hf;                             // exact residual
  unsigned ul = __float_as_uint(lo);
  l = (ushort_t)((ul + 0x7FFFu + ((ul >> 16) & 1u)) >> 16);  // RNE bf16 lo
}

__global__ __launch_bounds__(256) void gemm_mfma_kernel(
    const float* __restrict__ A, const float* __restrict__ W,
    const float* __restrict__ bias, float* __restrict__ out,
    int M, int K) {
  // A: [64 rows][40 k-pad] bf16 (hi,lo); B: [128 cols][40 k-pad] (hi,lo), XOR-swizzled granules
  __shared__ __align__(16) ushort_t Ahi[GBM][40], Alo[GBM][40];
  __shared__ __align__(16) ushort_t Bhi[128][40], Blo[128][40];

  const int tid  = threadIdx.x;
  const int row0 = blockIdx.x * GBM;

  // staging assignments
  const int arow = tid >> 2;            // 0..63
  const int akg  = (tid & 3) * 8;       // k-offset 0,8,16,24
  const int bcol = tid & 127;           // 0..127
  const int bkh  = tid >> 7;            // 0/1 -> k range [bkh*16, +16)
  const int bkey = (bcol >> 3) & 3;     // XOR swizzle key for B granules

  // wave/frag assignments
  const int lane = tid & 63;
  const int wv   = tid >> 6;
  const int r0w  = (wv >> 1) * 32;      // wave row base
  const int c0w  = (wv & 1) * 64;       // wave col base
  const int la   = lane & 15;
  const int hh   = lane >> 4;           // k-granule 0..3

  f32x4 acc[2][4];
#pragma unroll
  for (int m = 0; m < 2; ++m)
#pragma unroll
    for (int c = 0; c < 4; ++c) acc[m][c] = (f32x4){0.f, 0.f, 0.f, 0.f};

  const int nsteps = K / GKS;
  float4 av0, av1;
  float bw[16];

  // --- tile loader (global -> regs) ---
  auto load_tile = [&](int k0) {
    const int grow = row0 + arow;
    if (grow < M) {
      const float* ap = A + (size_t)grow * K + k0 + akg;
      av0 = *(const float4*)ap;
      av1 = *(const float4*)(ap + 4);
    } else {
      av0 = make_float4(0.f, 0.f, 0.f, 0.f);
      av1 = av0;
    }
#pragma unroll
    for (int j = 0; j < 16; ++j)
      bw[j] = W[(size_t)(k0 + bkh * 16 + j) * 128 + bcol];
  };

  load_tile(0);

  for (int s = 0; s < nsteps; ++s) {
    __syncthreads();   // prior tile's frag reads complete before overwrite
    // --- convert + LDS write ---
    {
      ushort_t h[8], l[8];
      const float va[8] = {av0.x, av0.y, av0.z, av0.w, av1.x, av1.y, av1.z, av1.w};
#pragma unroll
      for (int j = 0; j < 8; ++j) split2(va[j], h[j], l[j]);
      *(bf16x8*)&Ahi[arow][akg] = *(bf16x8*)h;
      *(bf16x8*)&Alo[arow][akg] = *(bf16x8*)l;
    }
    {
      ushort_t h[16], l[16];
#pragma unroll
      for (int j = 0; j < 16; ++j) split2(bw[j], h[j], l[j]);
      // two 8-bf16 granules per half, swizzled position
#pragma unroll
      for (int q = 0; q < 2; ++q) {
        const int g = bkh * 2 + q;               // logical granule 0..3
        const int gs = (g ^ bkey) * 8;           // swizzled k-offset
        *(bf16x8*)&Bhi[bcol][gs] = *(bf16x8*)&h[q * 8];
        *(bf16x8*)&Blo[bcol][gs] = *(bf16x8*)&l[q * 8];
      }
    }
    __syncthreads();

    if (s + 1 < nsteps) load_tile((s + 1) * GKS);   // overlap next loads with MFMA

    // --- fragment reads + MFMA ---
    bf16x8 fah[2], fal[2];
#pragma unroll
    for (int m = 0; m < 2; ++m) {
      fah[m] = *(const bf16x8*)&Ahi[r0w + m * 16 + la][hh * 8];
      fal[m] = *(const bf16x8*)&Alo[r0w + m * 16 + la][hh * 8];
    }
#pragma unroll
    for (int c = 0; c < 4; ++c) {
      const int col = c0w + c * 16 + la;
      const int gs = (hh ^ ((col >> 3) & 3)) * 8;
      const bf16x8 fbh = *(const bf16x8*)&Bhi[col][gs];
      const bf16x8 fbl = *(const bf16x8*)&Blo[col][gs];
#pragma unroll
      for (int m = 0; m < 2; ++m) {
        acc[m][c] = __builtin_amdgcn_mfma_f32_16x16x32_bf16(fah[m], fbh, acc[m][c], 0, 0, 0);
        acc[m][c] = __builtin_amdgcn_mfma_f32_16x16x32_bf16(fah[m], fbl, acc[m][c], 0, 0, 0);
        acc[m][c] = __builtin_amdgcn_mfma_f32_16x16x32_bf16(fal[m], fbh, acc[m][c], 0, 0, 0);
      }
    }
  }

  // --- epilogue: C = acc + bias ---
#pragma unroll
  for (int c = 0; c < 4; ++c) {
    const int col = c0w + c * 16 + la;
    const float bv = bias[col];
#pragma unroll
    for (int m = 0; m < 2; ++m) {
      const int rbase = row0 + r0w + m * 16 + hh * 4;
#pragma unroll
      for (int j = 0; j < 4; ++j) {
        const int grow = rbase + j;
        if (grow < M) out[(size_t)grow * 128 + col] = acc[m][c][j] + bv;
      }
    }
  }
}

// ---------------------------------------------------------------------------
// Spectral kernel: 1 wave per row (4 rows / 256-thread block), in-place on d_out.
// rfft (ortho) -> rot/AVRF/MSC mask -> irfft (ortho).
// ---------------------------------------------------------------------------
__global__ __launch_bounds__(256) void spectral_kernel(
    float* io_img, float* io_txt,
    const float* __restrict__ avrf_img, const float* __restrict__ avrf_txt,
    const float* __restrict__ avg_R, const float* __restrict__ psi,
    const float* __restrict__ lamw, int M) {
  __shared__ float twc[128], tws[128];       // cos/sin(2*pi*n/128)
  __shared__ float xs[4][2][128];            // per wave: img,txt rows
  __shared__ float4 spec[4][66];             // per wave, per freq: (i_re,i_im,t_re,t_im)

  const int tid = threadIdx.x;
  if (tid < 128) {
    float s, c;
    sincosf(0.04908738521234052f * (float)tid, &s, &c);  // 2*pi/128
    twc[tid] = c; tws[tid] = s;
  }
  const int wave = tid >> 6;
  const int lane = tid & 63;
  const int row  = blockIdx.x * 4 + wave;
  const bool valid = row < M;

  if (valid) {
    const size_t base = (size_t)row * 128;
    xs[wave][0][lane]      = io_img[base + lane];
    xs[wave][0][lane + 64] = io_img[base + lane + 64];
    xs[wave][1][lane]      = io_txt[base + lane];
    xs[wave][1][lane + 64] = io_txt[base + lane + 64];
  } else {
    xs[wave][0][lane] = 0.f; xs[wave][0][lane + 64] = 0.f;
    xs[wave][1][lane] = 0.f; xs[wave][1][lane + 64] = 0.f;
  }
  __syncthreads();

  // ---- forward DFT: lane = freq k (0..63); X[k] = sum_n x[n] e^{-2pi i k n/128}
  const int k = lane;
  const float wr = twc[k], wi = -tws[k];     // e^{-2pi i k/128}
  float air = 0.f, aii = 0.f, atr = 0.f, ati = 0.f;
  for (int n8 = 0; n8 < 128; n8 += 8) {
    const int idx = (k * n8) & 127;          // resync rotation from table
    float cr = twc[idx], ci = -tws[idx];
    float xi[8], xt[8];
    *(float4*)&xi[0] = *(const float4*)&xs[wave][0][n8];
    *(float4*)&xi[4] = *(const float4*)&xs[wave][0][n8 + 4];
    *(float4*)&xt[0] = *(const float4*)&xs[wave][1][n8];
    *(float4*)&xt[4] = *(const float4*)&xs[wave][1][n8 + 4];
#pragma unroll
    for (int j = 0; j < 8; ++j) {
      air = fmaf(xi[j], cr, air);
      aii = fmaf(xi[j], ci, aii);
      atr = fmaf(xt[j], cr, atr);
      ati = fmaf(xt[j], ci, ati);
      if (j < 7) {
        const float ncr = cr * wr - ci * wi;
        ci = cr * wi + ci * wr;
        cr = ncr;
      }
    }
  }
  // ---- Nyquist bin X[64] = sum_n (-1)^n x[n] (purely real): parity shuffle-reduce
  float pi_ = xs[wave][0][lane] + xs[wave][0][lane + 64];
  float pt_ = xs[wave][1][lane] + xs[wave][1][lane + 64];
  if (lane & 1) { pi_ = -pi_; pt_ = -pt_; }
#pragma unroll
  for (int off = 32; off > 0; off >>= 1) {
    pi_ += __shfl_xor(pi_, off);
    pt_ += __shfl_xor(pt_, off);
  }
  const float scale = 0.08838834764831845f;  // 1/sqrt(128)  (norm="ortho")
  air *= scale; aii *= scale; atr *= scale; ati *= scale;
  pi_ *= scale; pt_ *= scale;

  // lambda softmax (uniform across lanes)
  const float l0 = lamw[0], l1 = lamw[1];
  const float mxl = fmaxf(l0, l1);
  const float e0 = expf(l0 - mxl), e1 = expf(l1 - mxl);
  const float inv = 1.f / (e0 + e1);
  const float lam0 = e0 * inv, lam1 = e1 * inv;

  // ---- rotation + AVRF + MSC mask, freq k (lane-local)
  {
    const float phi = avg_R[k] * 0.5f + psi[k];
    float sp, cp; sincosf(phi, &sp, &cp);
    // rot = e^{-i phi}; APC_img = X_img * rot; APC_txt = X_txt * conj(rot)
    const float Air = air * cp + aii * sp;
    const float Aii = aii * cp - air * sp;
    const float Atr = atr * cp - ati * sp;
    const float Ati = ati * cp + atr * sp;
    const float cre = Air * Atr + Aii * Ati;
    const float cim = Aii * Atr - Air * Ati;
    const float pa = Air * Air + Aii * Aii;
    const float pb = Atr * Atr + Ati * Ati;
    const float msc = (cre * cre + cim * cim) / (pa * pb + 1e-8f);
    const float mi = lam0 * avrf_img[k] + lam1 * msc;
    const float mt = lam0 * avrf_txt[k] + lam1 * msc;
    spec[wave][k] = make_float4(Air * mi, Aii * mi, Atr * mt, Ati * mt);
  }
  if (lane == 0) {   // freq 64 (Nyquist)
    const float phi = avg_R[64] * 0.5f + psi[64];
    float sp, cp; sincosf(phi, &sp, &cp);
    const float Air = pi_ * cp;
    const float Aii = -pi_ * sp;
    const float Atr = pt_ * cp;
    const float Ati = pt_ * sp;
    const float cre = Air * Atr + Aii * Ati;
    const float cim = Aii * Atr - Air * Ati;
    const float pa = Air * Air + Aii * Aii;
    const float pb = Atr * Atr + Ati * Ati;
    const float msc = (cre * cre + cim * cim) / (pa * pb + 1e-8f);
    const float mi = lam0 * avrf_img[64] + lam1 * msc;
    const float mt = lam0 * avrf_txt[64] + lam1 * msc;
    spec[wave][64] = make_float4(Air * mi, Aii * mi, Atr * mt, Ati * mt);
  }
  __syncthreads();

  // ---- irfft (ortho): lane n produces out[n] and out[n+64]
  const int n = lane;
  const float4 s0  = spec[wave][0];
  const float4 s64 = spec[wave][64];
  const float sgn = (n & 1) ? -1.f : 1.f;
  const float basei = s0.x + sgn * s64.x;
  const float baset = s0.z + sgn * s64.z;
  const float iwr = twc[n], iwi = tws[n];    // e^{+2pi i n/128}
  float tei = 0.f, toi = 0.f, tet = 0.f, tot = 0.f;
  for (int k8 = 0; k8 < 64; k8 += 8) {
    const int idx = (n * k8) & 127;
    float cr = twc[idx], ci = tws[idx];
#pragma unroll
    for (int j = 0; j < 8; ++j) {
      const int kk = k8 + j;
      if (kk >= 1) {
        const float4 sp4 = spec[wave][kk];
        const float ti = sp4.x * cr - sp4.y * ci;
        const float tt = sp4.z * cr - sp4.w * ci;
        if (kk & 1) { toi += ti; tot += tt; }
        else        { tei += ti; tet += tt; }
      }
      const float ncr = cr * iwr - ci * iwi;
      ci = cr * iwi + ci * iwr;
      cr = ncr;
    }
  }
  if (valid) {
    const size_t base = (size_t)row * 128;
    io_img[base + n]      = scale * (basei + 2.f * (tei + toi));
    io_img[base + n + 64] = scale * (basei + 2.f * (tei - toi));
    io_txt[base + n]      = scale * (baset + 2.f * (tet + tot));
    io_txt[base + n + 64] = scale * (baset + 2.f * (tet - tot));
  }
}

extern "C" void kernel_launch(void* const* d_in, const int* in_sizes, int n_in,
                              void* d_out, int out_size, void* d_ws, size_t ws_size,
                              hipStream_t stream) {
  const float* image_table = (const float*)d_in[2];
  const float* text_table  = (const float*)d_in[3];
  const float* W_img = (const float*)d_in[4];
  const float* b_img = (const float*)d_in[5];
  const float* W_txt = (const float*)d_in[6];
  const float* b_txt = (const float*)d_in[7];
  const float* avrf_img = (const float*)d_in[8];
  const float* avrf_txt = (const float*)d_in[9];
  const float* avg_R = (const float*)d_in[10];
  const float* psi = (const float*)d_in[11];
  const float* lamw = (const float*)d_in[12];

  const int M = in_sizes[0] / 128;        // 30000
  const int K_img = in_sizes[4] / 128;    // 1024
  const int K_txt = in_sizes[6] / 128;    // 768

  float* out_img = (float*)d_out;               // proj staged here, transformed in place
  float* out_txt = out_img + (size_t)M * 128;

  const dim3 blk(256);
  const int gblocks = (M + GBM - 1) / GBM;
  gemm_mfma_kernel<<<gblocks, blk, 0, stream>>>(image_table, W_img, b_img, out_img, M, K_img);
  gemm_mfma_kernel<<<gblocks, blk, 0, stream>>>(text_table,  W_txt, b_txt, out_txt, M, K_txt);
  spectral_kernel<<<(M + 3) / 4, blk, 0, stream>>>(out_img, out_txt,
                                                   avrf_img, avrf_txt, avg_R, psi, lamw, M);
}

// Round 3
// 133.595 us; speedup vs baseline: 2.4258x; 1.6469x over previous
//
#include <hip/hip_runtime.h>
#include <math.h>

typedef __bf16 bf16x8 __attribute__((ext_vector_type(8)));
typedef float f32x4 __attribute__((ext_vector_type(4)));
typedef unsigned short ushort_t;

#define BM 64
#define KS 32
#define S128 0.08838834764831845f       // 1/sqrt(128)
#define TWOPI_128 0.04908738521234052f  // 2*pi/128

// ---------------------------------------------------------------------------
// Device-global precomputed operands (written by setup kernels every launch).
// WFT chunks: per k-step s and plane h (hi/lo): [192 cols][32 k] ushorts.
// GT  chunks: per k-step s, plane h:            [128 cols][32 k] ushorts.
// fp: per freq k (0..95): {rotc, rots, avrfI, avrfT, bIre, bIim, bTre, bTim}
// ---------------------------------------------------------------------------
__device__ __align__(16) ushort_t g_wft[(32 + 24) * 2 * 6144];
__device__ __align__(16) ushort_t g_gt[6 * 2 * 4096];
__device__ float g_fp[96 * 8];
__device__ unsigned g_spill[512 * 12288];   // per-block S_img spill (hi<<16|lo)

__device__ __forceinline__ void split2(float v, ushort_t& h, ushort_t& l) {
  unsigned u = __float_as_uint(v);
  h = (ushort_t)(u >> 16);
  float hf = __uint_as_float(u & 0xFFFF0000u);
  float lo = v - hf;
  unsigned ul = __float_as_uint(lo);
  l = (ushort_t)((ul + 0x7FFFu + ((ul >> 16) & 1u)) >> 16);
}

__device__ __forceinline__ void gll16(const void* gsrc, void* ldst) {
  __builtin_amdgcn_global_load_lds(
      (const __attribute__((address_space(1))) unsigned int*)gsrc,
      (__attribute__((address_space(3))) unsigned int*)ldst, 16, 0, 0);
}

// ---------------------------------------------------------------------------
// Setup: WF = W @ F (ortho rfft matrix), split bf16 hi/lo, chunked layout.
// phys col c: group=c>>5, part=(c>>4)&1 (0 re, 1 im), freq=group*16+(c&15).
// ---------------------------------------------------------------------------
__global__ void k_setup_wft(const float* __restrict__ Wimg,
                            const float* __restrict__ Wtxt, int Kimg, int Ktxt) {
  int gid = blockIdx.x * 256 + threadIdx.x;
  int imgn = Kimg * 192;
  if (gid >= imgn + Ktxt * 192) return;
  const float* W;
  int k, c;
  ushort_t* base;
  if (gid < imgn) {
    k = gid / 192; c = gid % 192; W = Wimg + (size_t)k * 128; base = g_wft;
  } else {
    int l = gid - imgn;
    k = l / 192; c = l % 192; W = Wtxt + (size_t)k * 128;
    base = g_wft + (size_t)(Kimg / 32) * 12288;
  }
  int grp = c >> 5, wi = c & 31, part = wi >> 4, fl = grp * 16 + (wi & 15);
  float val = 0.f;
  if (fl <= 64) {
    float re = 0.f, im = 0.f;
    float sts, stc;
    sincosf(TWOPI_128 * (float)fl, &sts, &stc);   // step e^{-i a} = (stc, -sts)
    for (int d0 = 0; d0 < 128; d0 += 16) {
      int m = (fl * d0) & 127;
      float sa, ca;
      sincosf(TWOPI_128 * (float)m, &sa, &ca);
      float cr = ca, ci = -sa;
#pragma unroll
      for (int j = 0; j < 16; ++j) {
        float w = W[d0 + j];
        re = fmaf(w, cr, re);
        im = fmaf(w, ci, im);
        float nc = cr * stc + ci * sts;
        ci = ci * stc - cr * sts;
        cr = nc;
      }
    }
    val = (part == 0 ? re : im) * S128;
  }
  ushort_t h, l;
  split2(val, h, l);
  int ks = k >> 5, kin = k & 31;
  base[(size_t)(ks * 2 + 0) * 6144 + c * 32 + kin] = h;
  base[(size_t)(ks * 2 + 1) * 6144 + c * 32 + kin] = l;
}

// G (ortho irfft expansion): out[n] = s*sum_k ck*(Re cos - Im sin), ck={1,2,..,1}
__global__ void k_setup_gt(void) {
  int gid = blockIdx.x * 256 + threadIdx.x;
  if (gid >= 192 * 128) return;
  int pk = gid >> 7, n = gid & 127;
  int grp = pk >> 5, wi = pk & 31, part = wi >> 4, fl = grp * 16 + (wi & 15);
  float val = 0.f;
  if (fl <= 64) {
    float ck = (fl == 0 || fl == 64) ? 1.f : 2.f;
    int m = (fl * n) & 127;
    float sa, ca;
    sincosf(TWOPI_128 * (float)m, &sa, &ca);
    val = (part == 0 ? ca : -sa) * ck * S128;
  }
  ushort_t h, l;
  split2(val, h, l);
  g_gt[(size_t)(grp * 2 + 0) * 4096 + n * 32 + wi] = h;
  g_gt[(size_t)(grp * 2 + 1) * 4096 + n * 32 + wi] = l;
}

__global__ void k_setup_fp(const float* __restrict__ b_img, const float* __restrict__ b_txt,
                           const float* __restrict__ avrf_img, const float* __restrict__ avrf_txt,
                           const float* __restrict__ avg_R, const float* __restrict__ psi) {
  int gid = blockIdx.x * 256 + threadIdx.x;
  if (gid >= 96 * 4) return;
  int k = gid >> 2, q = gid & 3;
  float* fp = g_fp + k * 8;
  if (k > 64) {
    if (q == 0) { fp[0] = 1.f; fp[1] = 0.f; fp[2] = 0.f; fp[3] = 0.f; }
    fp[4 + q] = 0.f;
    return;
  }
  if (q == 0) {
    float phi = avg_R[k] * 0.5f + psi[k];
    float s, c;
    sincosf(phi, &s, &c);
    fp[0] = c; fp[1] = s; fp[2] = avrf_img[k]; fp[3] = avrf_txt[k];
  }
  const float* b = (q < 2) ? b_img : b_txt;
  int part = q & 1;
  float acc = 0.f;
  for (int d = 0; d < 128; ++d) {
    int m = (k * d) & 127;
    float sa, ca;
    sincosf(TWOPI_128 * (float)m, &sa, &ca);
    acc = fmaf(b[d], part ? -sa : ca, acc);
  }
  fp[4 + q] = acc * S128;
}

// ---------------------------------------------------------------------------
// Fused: S_img = Aimg@WF+bF -> spill; S_txt = Atxt@WF+bF; mask; out = Y@G.
// 256 threads = 4 waves (2x2): wave = 32 rows x 96 phys cols (GEMM),
//                              32 rows x 64 out cols (iDFT).
// ---------------------------------------------------------------------------
__global__ __launch_bounds__(256, 2) void fused_kernel(
    const float* __restrict__ Aimg, const float* __restrict__ Atxt,
    const float* __restrict__ lamw, float* __restrict__ out,
    int M, int Kimg, int Ktxt) {
  __shared__ __align__(16) char smem[67584];
  float* A_lds = (float*)smem;                       // [2][64][32] fp32, slot-swizzled
  ushort_t* B_lds = (ushort_t*)(smem + 16384);       // [2][2][192][32]
  ushort_t* Yhi = (ushort_t*)smem;                   // [64][200]
  ushort_t* Ylo = (ushort_t*)(smem + 25600);
  ushort_t* G_lds = (ushort_t*)(smem + 51200);       // [2][128][32]

  const int tid = threadIdx.x, blk = blockIdx.x;
  const int lane = tid & 63, wv = tid >> 6;
  const int la = lane & 15, hh = lane >> 4;
  const int wr = wv >> 1, wc = wv & 1;
  const int row0 = blk * BM;

  f32x4 acc[2][6];

  auto stageA = [&](const float* A, int K, int s, int buf) {
#pragma unroll
    for (int i = 0; i < 2; ++i) {
      int idx = i * 256 + tid;
      int r = idx >> 3, sl = idx & 7;
      int kg = sl ^ (r & 7);                 // source-swizzle -> conflict-free reads
      int grow = row0 + r;
      if (grow > M - 1) grow = M - 1;
      const float* src = A + (size_t)grow * K + s * KS + kg * 4;
      char* dst = (char*)A_lds + buf * 8192 + i * 4096 + wv * 1024;
      gll16(src, dst);
    }
  };
  auto stageB = [&](const ushort_t* wft, int s, int buf) {
#pragma unroll
    for (int i = 0; i < 6; ++i) {
      const ushort_t* src = wft + (size_t)s * 12288 + i * 2048 + tid * 8;
      char* dst = (char*)B_lds + buf * 24576 + i * 4096 + wv * 1024;
      gll16(src, dst);
    }
  };

  auto gemm = [&](const float* A, int K, const ushort_t* wft) {
#pragma unroll
    for (int rt = 0; rt < 2; ++rt)
#pragma unroll
      for (int ct = 0; ct < 6; ++ct) acc[rt][ct] = (f32x4){0.f, 0.f, 0.f, 0.f};
    const int nst = K / KS;
    stageA(A, K, 0, 0);
    stageB(wft, 0, 0);
    for (int s = 0; s < nst; ++s) {
      const int cur = s & 1;
      __syncthreads();                       // drains gll (vmcnt) + orders buffers
      if (s + 1 < nst) { stageA(A, K, s + 1, cur ^ 1); stageB(wft, s + 1, cur ^ 1); }
      bf16x8 fah[2], fal[2];
#pragma unroll
      for (int rt = 0; rt < 2; ++rt) {
        int row = wr * 32 + rt * 16 + la;
        const float* ab = A_lds + cur * 2048 + row * 32;
        int s0 = (2 * hh) ^ (row & 7);
        int s1 = s0 ^ 1;
        f32x4 q0 = *(const f32x4*)(ab + s0 * 4);
        f32x4 q1 = *(const f32x4*)(ab + s1 * 4);
        ushort_t h8[8], l8[8];
#pragma unroll
        for (int j = 0; j < 4; ++j) {
          split2(q0[j], h8[j], l8[j]);
          split2(q1[j], h8[4 + j], l8[4 + j]);
        }
        fah[rt] = *(bf16x8*)h8;
        fal[rt] = *(bf16x8*)l8;
      }
#pragma unroll
      for (int ct = 0; ct < 6; ++ct) {
        int pcol = wc * 96 + ct * 16 + la;
        const ushort_t* bb = B_lds + cur * 12288 + pcol * 32 + hh * 8;
        bf16x8 fbh = *(const bf16x8*)bb;
        bf16x8 fbl = *(const bf16x8*)(bb + 6144);
#pragma unroll
        for (int rt = 0; rt < 2; ++rt) {
          acc[rt][ct] = __builtin_amdgcn_mfma_f32_16x16x32_bf16(fah[rt], fbh, acc[rt][ct], 0, 0, 0);
          acc[rt][ct] = __builtin_amdgcn_mfma_f32_16x16x32_bf16(fah[rt], fbl, acc[rt][ct], 0, 0, 0);
          acc[rt][ct] = __builtin_amdgcn_mfma_f32_16x16x32_bf16(fal[rt], fbh, acc[rt][ct], 0, 0, 0);
        }
      }
    }
  };

  auto idft = [&](float* outp) {
    f32x4 acc2[2][4];
#pragma unroll
    for (int rt = 0; rt < 2; ++rt)
#pragma unroll
      for (int ct = 0; ct < 4; ++ct) acc2[rt][ct] = (f32x4){0.f, 0.f, 0.f, 0.f};
    for (int ks = 0; ks < 6; ++ks) {
      __syncthreads();                       // prior readers done / Y writes visible
#pragma unroll
      for (int i = 0; i < 4; ++i) {
        const ushort_t* src = g_gt + (size_t)ks * 8192 + i * 2048 + tid * 8;
        char* dst = (char*)G_lds + i * 4096 + wv * 1024;
        gll16(src, dst);
      }
      __syncthreads();                       // G landed
      bf16x8 yah[2], yal[2];
#pragma unroll
      for (int rt = 0; rt < 2; ++rt) {
        int row = wr * 32 + rt * 16 + la;
        int yb = row * 200 + ks * 32 + hh * 8;
        yah[rt] = *(const bf16x8*)&Yhi[yb];
        yal[rt] = *(const bf16x8*)&Ylo[yb];
      }
#pragma unroll
      for (int ct = 0; ct < 4; ++ct) {
        int col = wc * 64 + ct * 16 + la;
        const ushort_t* gb = G_lds + col * 32 + hh * 8;
        bf16x8 gbh = *(const bf16x8*)gb;
        bf16x8 gbl = *(const bf16x8*)(gb + 4096);
#pragma unroll
        for (int rt = 0; rt < 2; ++rt) {
          acc2[rt][ct] = __builtin_amdgcn_mfma_f32_16x16x32_bf16(yah[rt], gbh, acc2[rt][ct], 0, 0, 0);
          acc2[rt][ct] = __builtin_amdgcn_mfma_f32_16x16x32_bf16(yah[rt], gbl, acc2[rt][ct], 0, 0, 0);
          acc2[rt][ct] = __builtin_amdgcn_mfma_f32_16x16x32_bf16(yal[rt], gbh, acc2[rt][ct], 0, 0, 0);
        }
      }
    }
#pragma unroll
    for (int rt = 0; rt < 2; ++rt)
#pragma unroll
      for (int ct = 0; ct < 4; ++ct)
#pragma unroll
        for (int j = 0; j < 4; ++j) {
          int row = row0 + wr * 32 + rt * 16 + hh * 4 + j;
          if (row < M) outp[(size_t)row * 128 + wc * 64 + ct * 16 + la] = acc2[rt][ct][j];
        }
  };

  // ---------- phase 1a: img GEMM + spill ----------
  gemm(Aimg, Kimg, g_wft);
#pragma unroll
  for (int rt = 0; rt < 2; ++rt)
#pragma unroll
    for (int ct = 0; ct < 6; ++ct)
#pragma unroll
      for (int j = 0; j < 4; ++j) {
        ushort_t h, l;
        split2(acc[rt][ct][j], h, l);
        g_spill[(size_t)blk * 12288 + ((rt * 6 + ct) * 4 + j) * 256 + tid] =
            ((unsigned)h << 16) | l;
      }
  // ---------- phase 1b: txt GEMM ----------
  gemm(Atxt, Ktxt, g_wft + (size_t)(Kimg / 32) * 12288);
  __syncthreads();   // all waves done with A/B LDS before Y-area writes

  // ---------- phase 2: rotate + AVRF + MSC mask (lane-local) ----------
  float l0 = lamw[0], l1 = lamw[1];
  float mx = fmaxf(l0, l1);
  float e0 = expf(l0 - mx), e1 = expf(l1 - mx);
  float lam0 = e0 / (e0 + e1), lam1 = e1 / (e0 + e1);
#pragma unroll
  for (int rt = 0; rt < 2; ++rt)
#pragma unroll
    for (int g = 0; g < 3; ++g) {
      int k = (wc * 3 + g) * 16 + la;
      const float* fp = g_fp + k * 8;
      float rc = fp[0], rs = fp[1], avI = fp[2], avT = fp[3];
      float bIr = fp[4], bIi = fp[5], bTr = fp[6], bTi = fp[7];
#pragma unroll
      for (int j = 0; j < 4; ++j) {
        unsigned uir = g_spill[(size_t)blk * 12288 + ((rt * 6 + 2 * g) * 4 + j) * 256 + tid];
        unsigned uii = g_spill[(size_t)blk * 12288 + ((rt * 6 + 2 * g + 1) * 4 + j) * 256 + tid];
        float Sir = __uint_as_float(uir & 0xFFFF0000u) + __uint_as_float(uir << 16) + bIr;
        float Sii = __uint_as_float(uii & 0xFFFF0000u) + __uint_as_float(uii << 16) + bIi;
        float Str = acc[rt][2 * g][j] + bTr;
        float Sti = acc[rt][2 * g + 1][j] + bTi;
        float Air = Sir * rc + Sii * rs, Aii = Sii * rc - Sir * rs;   // * e^{-i phi}
        float Atr = Str * rc - Sti * rs, Ati = Sti * rc + Str * rs;   // * conj
        float cre = Air * Atr + Aii * Ati, cim = Aii * Atr - Air * Ati;
        float pa = Air * Air + Aii * Aii, pb = Atr * Atr + Ati * Ati;
        float msc = (cre * cre + cim * cim) / (pa * pb + 1e-8f);
        float mi = lam0 * avI + lam1 * msc, mt = lam0 * avT + lam1 * msc;
        int row = wr * 32 + rt * 16 + hh * 4 + j;
        int pc = (wc * 3 + g) * 32 + la;
        ushort_t yh, yl;
        split2(Air * mi, yh, yl); Yhi[row * 200 + pc] = yh; Ylo[row * 200 + pc] = yl;
        split2(Aii * mi, yh, yl); Yhi[row * 200 + pc + 16] = yh; Ylo[row * 200 + pc + 16] = yl;
        acc[rt][2 * g][j] = Atr * mt;        // Y_txt kept in registers
        acc[rt][2 * g + 1][j] = Ati * mt;
      }
    }

  // ---------- phase 3: iDFT via MFMA ----------
  idft(out);                       // img
  __syncthreads();                 // 3a reads done before Y overwrite
#pragma unroll
  for (int rt = 0; rt < 2; ++rt)
#pragma unroll
    for (int g = 0; g < 3; ++g)
#pragma unroll
      for (int j = 0; j < 4; ++j) {
        int row = wr * 32 + rt * 16 + hh * 4 + j;
        int pc = (wc * 3 + g) * 32 + la;
        ushort_t yh, yl;
        split2(acc[rt][2 * g][j], yh, yl);
        Yhi[row * 200 + pc] = yh; Ylo[row * 200 + pc] = yl;
        split2(acc[rt][2 * g + 1][j], yh, yl);
        Yhi[row * 200 + pc + 16] = yh; Ylo[row * 200 + pc + 16] = yl;
      }
  idft(out + (size_t)M * 128);     // txt
}

extern "C" void kernel_launch(void* const* d_in, const int* in_sizes, int n_in,
                              void* d_out, int out_size, void* d_ws, size_t ws_size,
                              hipStream_t stream) {
  const float* image_table = (const float*)d_in[2];
  const float* text_table  = (const float*)d_in[3];
  const float* W_img = (const float*)d_in[4];
  const float* b_img = (const float*)d_in[5];
  const float* W_txt = (const float*)d_in[6];
  const float* b_txt = (const float*)d_in[7];
  const float* avrf_img = (const float*)d_in[8];
  const float* avrf_txt = (const float*)d_in[9];
  const float* avg_R = (const float*)d_in[10];
  const float* psi = (const float*)d_in[11];
  const float* lamw = (const float*)d_in[12];

  const int M = in_sizes[0] / 128;        // 30000
  const int K_img = in_sizes[4] / 128;    // 1024
  const int K_txt = in_sizes[6] / 128;    // 768

  int wft_threads = (K_img + K_txt) * 192;
  k_setup_wft<<<(wft_threads + 255) / 256, 256, 0, stream>>>(W_img, W_txt, K_img, K_txt);
  k_setup_gt<<<(192 * 128 + 255) / 256, 256, 0, stream>>>();
  k_setup_fp<<<2, 256, 0, stream>>>(b_img, b_txt, avrf_img, avrf_txt, avg_R, psi);
  fused_kernel<<<(M + BM - 1) / BM, 256, 0, stream>>>(
      image_table, text_table, lamw, (float*)d_out, M, K_img, K_txt);
}